// Round 2
// baseline (260.444 us; speedup 1.0000x reference)
//
#include <hip/hip_runtime.h>

#define OUT_HW    14
#define NBINS     196     // 14*14
#define C_TOTAL   256
#define C_PER_BLK 64
#define NBOXES    512

__device__ __forceinline__ void axis_entry(float coord, float L,
                                           int& lo, int& hi, float& wlo, float& whi) {
    // torchvision ROIAlign bilinear edge handling
    const bool valid = (coord >= -1.0f) && (coord <= L);
    const float c   = fminf(fmaxf(coord, 0.0f), L - 1.0f);
    const float flo = floorf(c);
    const float fhi = fminf(flo + 1.0f, L - 1.0f);
    whi = c - flo;
    wlo = 1.0f - whi;
    if (!valid) { wlo = 0.0f; whi = 0.0f; }
    lo = (int)flo;
    hi = (int)fhi;
}

#define ISSUE(S, fp) do { \
    S##0  = (fp)[o00]; S##1  = (fp)[o01]; S##2  = (fp)[o02]; S##3  = (fp)[o03]; \
    S##4  = (fp)[o10]; S##5  = (fp)[o11]; S##6  = (fp)[o12]; S##7  = (fp)[o13]; \
    S##8  = (fp)[o20]; S##9  = (fp)[o21]; S##10 = (fp)[o22]; S##11 = (fp)[o23]; \
    S##12 = (fp)[o30]; S##13 = (fp)[o31]; S##14 = (fp)[o32]; S##15 = (fp)[o33]; \
} while (0)

#define COMPUTE(S) \
    ( wy0 * (wx0 * S##0  + wx1 * S##1  + wx2 * S##2  + wx3 * S##3 ) \
    + wy1 * (wx0 * S##4  + wx1 * S##5  + wx2 * S##6  + wx3 * S##7 ) \
    + wy2 * (wx0 * S##8  + wx1 * S##9  + wx2 * S##10 + wx3 * S##11) \
    + wy3 * (wx0 * S##12 + wx1 * S##13 + wx2 * S##14 + wx3 * S##15) )

__global__ __launch_bounds__(256) void roi_pool_kernel(
    const float* __restrict__ x0, const float* __restrict__ x1,
    const float* __restrict__ x2, const float* __restrict__ x3,
    const float* __restrict__ boxes, float* __restrict__ out)
{
    const int m    = blockIdx.x;   // box
    const int cblk = blockIdx.y;   // 64-channel chunk

    // ---- block-uniform box/level setup ----
    const float b0  = boxes[m * 5 + 0];
    const float bx0 = boxes[m * 5 + 1];
    const float by0 = boxes[m * 5 + 2];
    const float bx1 = boxes[m * 5 + 3];
    const float by1 = boxes[m * 5 + 4];

    const float sz = sqrtf((bx1 - bx0) * (by1 - by0));
    int lvl = (int)floorf(4.0f + log2f(sz * (1.0f / 224.0f) + 1e-8f));
    lvl = min(max(lvl, 2), 5) - 2;

    const float scales[4] = {0.25f, 0.125f, 0.0625f, 0.03125f};
    const int   dims[4]   = {256, 128, 64, 32};
    const float scale = scales[lvl];
    const int   W = dims[lvl];
    const int   H = W;
    const int   HW = W * W;
    const float* feat = (lvl == 0) ? x0 : (lvl == 1) ? x1 : (lvl == 2) ? x2 : x3;
    const int bidx = (int)b0;

    const float rx0 = bx0 * scale - 0.5f;
    const float ry0 = by0 * scale - 0.5f;
    const float binw = (bx1 * scale - 0.5f - rx0) * (1.0f / (float)OUT_HW);
    const float binh = (by1 * scale - 0.5f - ry0) * (1.0f / (float)OUT_HW);

    // ---- per-thread bin setup (once) ----
    const int  tid    = threadIdx.x;
    const bool active = (tid < NBINS);
    const int  t  = active ? tid : (NBINS - 1);
    const int  ph = t / OUT_HW;
    const int  pw = t - ph * OUT_HW;

    // sample positions: bin + {0.25, 0.75}
    const float ysc0 = ry0 + ((float)ph + 0.25f) * binh;
    const float ysc1 = ry0 + ((float)ph + 0.75f) * binh;
    const float xsc0 = rx0 + ((float)pw + 0.25f) * binw;
    const float xsc1 = rx0 + ((float)pw + 0.75f) * binw;

    int yl0, yh0, yl1, yh1, xl0, xh0, xl1, xh1;
    float wy0, wy1, wy2, wy3, wx0, wx1, wx2, wx3;
    axis_entry(ysc0, (float)H, yl0, yh0, wy0, wy1);
    axis_entry(ysc1, (float)H, yl1, yh1, wy2, wy3);
    axis_entry(xsc0, (float)W, xl0, xh0, wx0, wx1);
    axis_entry(xsc1, (float)W, xl1, xh1, wx2, wx3);

    // fold the 2x2-sample mean into the y-weights
    wy0 *= 0.25f; wy1 *= 0.25f; wy2 *= 0.25f; wy3 *= 0.25f;

    const int r0 = yl0 * W, r1 = yh0 * W, r2 = yl1 * W, r3 = yh1 * W;
    const int o00 = r0 + xl0, o01 = r0 + xh0, o02 = r0 + xl1, o03 = r0 + xh1;
    const int o10 = r1 + xl0, o11 = r1 + xh0, o12 = r1 + xl1, o13 = r1 + xh1;
    const int o20 = r2 + xl0, o21 = r2 + xh0, o22 = r2 + xl1, o23 = r2 + xh1;
    const int o30 = r3 + xl0, o31 = r3 + xh0, o32 = r3 + xl1, o33 = r3 + xh1;

    const float* fb = feat + ((size_t)bidx * C_TOTAL + (size_t)cblk * C_PER_BLK) * HW;
    float* ob = out + ((size_t)m * C_TOTAL + (size_t)cblk * C_PER_BLK) * NBINS + tid;

    // ---- channel loop: 16 indep loads/iter, register double-buffered ----
    float A0,A1,A2,A3,A4,A5,A6,A7,A8,A9,A10,A11,A12,A13,A14,A15;
    float B0,B1,B2,B3,B4,B5,B6,B7,B8,B9,B10,B11,B12,B13,B14,B15;

    const float* fp = fb;
    ISSUE(A, fp); fp += HW;

    for (int c = 0; c < C_PER_BLK - 2; c += 2) {
        ISSUE(B, fp); fp += HW;
        const float vA = COMPUTE(A);
        if (active) ob[(size_t)c * NBINS] = vA;
        ISSUE(A, fp); fp += HW;
        const float vB = COMPUTE(B);
        if (active) ob[(size_t)(c + 1) * NBINS] = vB;
    }
    // last pair (c = 62, 63): no further prefetch
    ISSUE(B, fp);
    const float vA = COMPUTE(A);
    if (active) ob[(size_t)(C_PER_BLK - 2) * NBINS] = vA;
    const float vB = COMPUTE(B);
    if (active) ob[(size_t)(C_PER_BLK - 1) * NBINS] = vB;
}

extern "C" void kernel_launch(void* const* d_in, const int* in_sizes, int n_in,
                              void* d_out, int out_size, void* d_ws, size_t ws_size,
                              hipStream_t stream) {
    const float* x0    = (const float*)d_in[0];
    const float* x1    = (const float*)d_in[1];
    const float* x2    = (const float*)d_in[2];
    const float* x3    = (const float*)d_in[3];
    const float* boxes = (const float*)d_in[4];
    float* out = (float*)d_out;

    dim3 grid(NBOXES, C_TOTAL / C_PER_BLK);
    dim3 block(256);
    roi_pool_kernel<<<grid, block, 0, stream>>>(x0, x1, x2, x3, boxes, out);
}

// Round 3
// 129.157 us; speedup vs baseline: 2.0165x; 2.0165x over previous
//
#include <hip/hip_runtime.h>
#include <stdint.h>

#define OUT_HW    14
#define NBINS     196     // 14*14
#define C_TOTAL   256
#define C_PER_BLK 64
#define NBOXES    512
#define TILE_W    64      // words per LDS tile row
#define TILE_R    56      // max staged rows (28 samples * lo/hi)
#define TILE_WORDS (TILE_R * TILE_W)   // 3584 words = 14336 B per buffer

__device__ __forceinline__ void axis_entry(float coord, float L,
                                           int& lo, int& hi, float& wlo, float& whi) {
    // torchvision ROIAlign bilinear edge handling
    const bool valid = (coord >= -1.0f) && (coord <= L);
    const float c   = fminf(fmaxf(coord, 0.0f), L - 1.0f);
    const float flo = floorf(c);
    const float fhi = fminf(flo + 1.0f, L - 1.0f);
    whi = c - flo;
    wlo = 1.0f - whi;
    if (!valid) { wlo = 0.0f; whi = 0.0f; }
    lo = (int)flo;
    hi = (int)fhi;
}

// feature index (lo if sl even, hi if sl odd) of 1-D sample sl>>1
__device__ __forceinline__ int sample_idx(int sl, float org, float bin, float L) {
    const int s = sl >> 1;
    const float coord = org + (0.5f * (float)s + 0.25f) * bin;
    int lo, hi; float a, b;
    axis_entry(coord, L, lo, hi, a, b);
    return (sl & 1) ? hi : lo;
}

__device__ __forceinline__ void load_lds4(const float* g, float* l) {
    __builtin_amdgcn_global_load_lds(
        (const __attribute__((address_space(1))) void*)g,
        (__attribute__((address_space(3))) void*)l, 4, 0, 0);
}

__global__ __launch_bounds__(256) void roi_pool_kernel(
    const float* __restrict__ x0, const float* __restrict__ x1,
    const float* __restrict__ x2, const float* __restrict__ x3,
    const float* __restrict__ boxes, float* __restrict__ out)
{
    __shared__ float tile[2][TILE_WORDS];

    const int m    = blockIdx.x;   // box
    const int cblk = blockIdx.y;   // 64-channel chunk
    const int tid  = threadIdx.x;

    // ---- block-uniform box/level setup ----
    const float bxi = boxes[m*5+0];
    const float bx0 = boxes[m*5+1];
    const float by0 = boxes[m*5+2];
    const float bx1 = boxes[m*5+3];
    const float by1 = boxes[m*5+4];

    const float sz = sqrtf((bx1 - bx0) * (by1 - by0));
    int lvl = (int)floorf(4.0f + log2f(sz * (1.0f/224.0f) + 1e-8f));
    lvl = min(max(lvl, 2), 5) - 2;

    const float scales[4] = {0.25f, 0.125f, 0.0625f, 0.03125f};
    const int   dims[4]   = {256, 128, 64, 32};
    const float scale = scales[lvl];
    const int   W  = dims[lvl];
    const int   HW = W * W;
    const float Lf = (float)W;
    const float* feat = (lvl == 0) ? x0 : (lvl == 1) ? x1 : (lvl == 2) ? x2 : x3;
    const int bidx = (int)bxi;

    const float rx0 = bx0*scale - 0.5f;
    const float ry0 = by0*scale - 0.5f;
    const float binw = (bx1*scale - 0.5f - rx0) * (1.0f/14.0f);
    const float binh = (by1*scale - 0.5f - ry0) * (1.0f/14.0f);

    // uniform row/col extents (samples are monotone: first lo / last hi)
    int ymin, ymax, xmin, xmax;
    {
        int lo, hi; float a, b;
        axis_entry(ry0 +  0.25f*binh, Lf, lo, hi, a, b); ymin = lo;
        axis_entry(ry0 + 13.75f*binh, Lf, lo, hi, a, b); ymax = hi;
        axis_entry(rx0 +  0.25f*binw, Lf, lo, hi, a, b); xmin = lo;
        axis_entry(rx0 + 13.75f*binw, Lf, lo, hi, a, b); xmax = hi;
    }
    const int  spany = ymax - ymin;
    const int  spanx = xmax - xmin;
    const bool cgY = (spany < TILE_R);   // contiguous-row staging
    const bool cgX = (spanx < TILE_R);   // contiguous-col addressing
    const int  NR  = cgY ? (spany + 1) : TILE_R;
    const int  K   = (NR + 3) >> 2;      // global_load_lds per thread per channel

    // ---- per-thread staging source offsets (constant across channels) ----
    int goff[14];
    #pragma unroll
    for (int k = 0; k < 14; ++k) {
        const int q  = tid + (k << 8);
        int slot = q >> 6;
        slot = min(slot, NR - 1);
        const int cp = q & 63;
        const int c  = cp ^ (slot & 31);   // de-swizzle: which logical col this word holds
        int col, row;
        if (cgX) col = xmin + min(c, spanx);
        else     col = sample_idx(min(c, 55), rx0, binw, Lf);
        if (cgY) row = ymin + slot;
        else     row = sample_idx(slot, ry0, binh, Lf);
        goff[k] = row * W + col;
    }

    // ---- per-thread tap setup (bin = thread) ----
    const bool active = (tid < NBINS);
    const int  t  = active ? tid : (NBINS - 1);
    const int  ph = t / OUT_HW;
    const int  pw = t - ph * OUT_HW;

    int yl0, yh0, yl1, yh1, xl0, xh0, xl1, xh1;
    float wy0, wy1, wy2, wy3, wx0, wx1, wx2, wx3;
    axis_entry(ry0 + ((float)ph + 0.25f)*binh, Lf, yl0, yh0, wy0, wy1);
    axis_entry(ry0 + ((float)ph + 0.75f)*binh, Lf, yl1, yh1, wy2, wy3);
    axis_entry(rx0 + ((float)pw + 0.25f)*binw, Lf, xl0, xh0, wx0, wx1);
    axis_entry(rx0 + ((float)pw + 0.75f)*binw, Lf, xl1, xh1, wx2, wx3);
    wy0 *= 0.25f; wy1 *= 0.25f; wy2 *= 0.25f; wy3 *= 0.25f;  // fold 2x2 mean

    int sr[4], cw[4];
    sr[0] = cgY ? (yl0 - ymin) : (4*ph + 0);
    sr[1] = cgY ? (yh0 - ymin) : (4*ph + 1);
    sr[2] = cgY ? (yl1 - ymin) : (4*ph + 2);
    sr[3] = cgY ? (yh1 - ymin) : (4*ph + 3);
    cw[0] = cgX ? (xl0 - xmin) : (4*pw + 0);
    cw[1] = cgX ? (xh0 - xmin) : (4*pw + 1);
    cw[2] = cgX ? (xl1 - xmin) : (4*pw + 2);
    cw[3] = cgX ? (xh1 - xmin) : (4*pw + 3);

    int woff[16];
    #pragma unroll
    for (int i = 0; i < 4; ++i)
        #pragma unroll
        for (int j = 0; j < 4; ++j)
            woff[i*4 + j] = sr[i]*TILE_W + (cw[j] ^ (sr[i] & 31));

    const float* fb = feat + ((size_t)bidx * C_TOTAL + (size_t)cblk * C_PER_BLK) * HW;
    float* ob = out + ((size_t)m * C_TOTAL + (size_t)cblk * C_PER_BLK) * NBINS + tid;

    // ---- prologue: stage channel 0 into buffer 0 ----
    {
        const float* fc = fb;
        #pragma unroll
        for (int k = 0; k < 14; ++k)
            if (k < K) load_lds4(fc + goff[k], &tile[0][tid + (k << 8)]);
    }

    // ---- channel loop: barrier (drains stage c) -> issue stage c+1 -> compute c ----
    #pragma unroll 2
    for (int c = 0; c < C_PER_BLK; ++c) {
        __syncthreads();   // waits vmcnt(0): stage(c) complete; all waves past compute(c-1)
        if (c + 1 < C_PER_BLK) {
            const float* fc = fb + (size_t)(c + 1) * HW;
            float* dst = &tile[(c + 1) & 1][0];
            #pragma unroll
            for (int k = 0; k < 14; ++k)
                if (k < K) load_lds4(fc + goff[k], dst + tid + (k << 8));
        }
        const float* bp = &tile[c & 1][0];
        const float v =
            wy0*(wx0*bp[woff[0]]  + wx1*bp[woff[1]]  + wx2*bp[woff[2]]  + wx3*bp[woff[3]])  +
            wy1*(wx0*bp[woff[4]]  + wx1*bp[woff[5]]  + wx2*bp[woff[6]]  + wx3*bp[woff[7]])  +
            wy2*(wx0*bp[woff[8]]  + wx1*bp[woff[9]]  + wx2*bp[woff[10]] + wx3*bp[woff[11]]) +
            wy3*(wx0*bp[woff[12]] + wx1*bp[woff[13]] + wx2*bp[woff[14]] + wx3*bp[woff[15]]);
        if (active) ob[(size_t)c * NBINS] = v;
    }
}

extern "C" void kernel_launch(void* const* d_in, const int* in_sizes, int n_in,
                              void* d_out, int out_size, void* d_ws, size_t ws_size,
                              hipStream_t stream) {
    const float* x0    = (const float*)d_in[0];
    const float* x1    = (const float*)d_in[1];
    const float* x2    = (const float*)d_in[2];
    const float* x3    = (const float*)d_in[3];
    const float* boxes = (const float*)d_in[4];
    float* out = (float*)d_out;

    dim3 grid(NBOXES, C_TOTAL / C_PER_BLK);
    dim3 block(256);
    roi_pool_kernel<<<grid, block, 0, stream>>>(x0, x1, x2, x3, boxes, out);
}